// Round 3
// baseline (945.789 us; speedup 1.0000x reference)
//
#include <hip/hip_runtime.h>

typedef unsigned short u16;
typedef unsigned int   u32;
typedef __attribute__((ext_vector_type(8))) short short8;
typedef __attribute__((ext_vector_type(4))) float f32x4;

#define NN   2024
#define NB   128
#define HID  128
#define MTOT (NN*NB)      // 259072
#define RPB  256          // rows per block
#define NBLK (MTOT/RPB)   // 1012

__device__ __forceinline__ float bflo(u32 w){ union{u32 u; float f;}c; c.u=w<<16;        return c.f; }
__device__ __forceinline__ float bfhi(u32 w){ union{u32 u; float f;}c; c.u=w&0xffff0000u; return c.f; }
__device__ __forceinline__ float bf2f(u16 h){ union{u32 u; float f;}c; c.u=((u32)h)<<16; return c.f; }
__device__ __forceinline__ u16 f2bf(float f){ union{float f; u32 u;}c; c.f=f; return (u16)((c.u+0x7fffu+((c.u>>16)&1u))>>16); }
__device__ __forceinline__ u32 cvtpk(float lo, float hi){
  u32 r; asm("v_cvt_pk_bf16_f32 %0, %1, %2" : "=v"(r) : "v"(lo), "v"(hi)); return r;
}
__device__ __forceinline__ f32x4 mfma16(short8 a, short8 b, f32x4 c){
  return __builtin_amdgcn_mfma_f32_16x16x32_bf16(a,b,c,0,0,0);
}

// weighted mean of 4 bf16x8 (weights include 1/cnt), repacked to bf16 RNE
__device__ __forceinline__ short8 avg4(short8 a0, short8 a1, short8 a2, short8 a3,
                                       float w0, float w1, float w2, float w3){
  union{short8 s; u32 u[4];} A, B, C, D, R;
  A.s=a0; B.s=a1; C.s=a2; D.s=a3;
#pragma unroll
  for (int p=0;p<4;++p){
    float lo = w0*bflo(A.u[p]); lo = fmaf(w1,bflo(B.u[p]),lo); lo = fmaf(w2,bflo(C.u[p]),lo); lo = fmaf(w3,bflo(D.u[p]),lo);
    float hi = w0*bfhi(A.u[p]); hi = fmaf(w1,bfhi(B.u[p]),hi); hi = fmaf(w2,bfhi(C.u[p]),hi); hi = fmaf(w3,bfhi(D.u[p]),hi);
    R.u[p] = cvtpk(lo, hi);
  }
  return R.s;
}

// h0 fragment: x*We[k..k+7] + be[k..k+7], packed bf16
__device__ __forceinline__ short8 synth8(float xv, const float* __restrict__ Wek,
                                         const float* __restrict__ bek){
  union{short8 s; u32 u[4];} R;
#pragma unroll
  for (int p=0;p<4;++p){
    float lo = fmaf(xv, Wek[2*p],   bek[2*p]);
    float hi = fmaf(xv, Wek[2*p+1], bek[2*p+1]);
    R.u[p] = cvtpk(lo, hi);
  }
  return R.s;
}

// One GNN layer, streaming: out = LN(relu([h, agg(h)] @ W + b)) * g + beta.
// Swapped MFMA operands: A = W^T (features as M), B = h rows (as N).
// 512 threads = 8 waves (4 row-groups x 2 feature-halves), wave tile 64 feat x 64 rows.
template<int EMBED>
__global__ __launch_bounds__(512, 4)
void layer2_k(const u16* __restrict__ hin, const float* __restrict__ x,
              const float* __restrict__ We, const float* __restrict__ be,
              const u16* __restrict__ Wt, const float* __restrict__ bias,
              const float* __restrict__ lng, const float* __restrict__ lnb,
              u16* __restrict__ hout)
{
  __shared__ __align__(16) u16 trBuf[RPB*128];   // 64KB; first 4KB doubles as LN red[]
  const int t  = threadIdx.x;
  const int l  = t & 63;
  const int wv = t >> 6, wr = wv >> 1, wc = wv & 1;
  const int cB = l & 15, rg = l >> 4;

  // bijective XCD swizzle: 1012 = 8*126 + 4
  const int orig = blockIdx.x;
  const int xcd = orig & 7, bidx = orig >> 3;
  const int swzb = (xcd < 4 ? xcd*127 : 508 + (xcd-4)*126) + bidx;
  const int m0 = swzb * RPB;
  const int rowb = m0 + 64*wr;

  // per-hm row info
  int   rowi[4], r0[4], r1[4], r2[4], r3[4];
  float fw0[4], fw1[4], fw2[4], fw3[4];
  float xs[4], mx[4];
#pragma unroll
  for (int hm=0; hm<4; ++hm){
    const int row = rowb + 16*hm + cB;
    rowi[hm] = row;
    const int nd = row % NN;
    const int v0 = (nd >= 45), v1 = (nd <= NN-46), v2 = (nd >= 1), v3 = (nd <= NN-2);
    const int cnt = v0+v1+v2+v3;
    const float inv = (cnt==4) ? 0.25f : ((cnt==3) ? (1.f/3.f) : 0.5f);
    fw0[hm] = v0 ? inv : 0.f; fw1[hm] = v1 ? inv : 0.f;
    fw2[hm] = v2 ? inv : 0.f; fw3[hm] = v3 ? inv : 0.f;
    r0[hm] = v0 ? row-45 : row; r1[hm] = v1 ? row+45 : row;
    r2[hm] = v2 ? row-1  : row; r3[hm] = v3 ? row+1  : row;
    if constexpr (EMBED){
      xs[hm] = x[row];
      mx[hm] = fw0[hm]*x[r0[hm]] + fw1[hm]*x[r1[hm]] + fw2[hm]*x[r2[hm]] + fw3[hm]*x[r3[hm]];
    }
  }

  f32x4 acc[4][4];
#pragma unroll
  for (int fj=0; fj<4; ++fj)
#pragma unroll
    for (int hm=0; hm<4; ++hm)
      acc[fj][hm] = (f32x4){0.f,0.f,0.f,0.f};

  const int kb = rg*8;

  // ---- chunk 0: self h ----
#pragma unroll
  for (int ks=0; ks<4; ++ks){
    const int kk = ks*32 + kb;
    short8 aW[4];
#pragma unroll
    for (int fj=0; fj<4; ++fj){
      const int feat = 64*wc + 16*fj + cB;
      aW[fj] = *(const short8*)(Wt + (u32)feat*256 + kk);
    }
#pragma unroll
    for (int hm=0; hm<4; ++hm){
      short8 bH;
      if constexpr (EMBED) bH = synth8(xs[hm], We+kk, be+kk);
      else                 bH = *(const short8*)(hin + (size_t)rowi[hm]*HID + kk);
#pragma unroll
      for (int fj=0; fj<4; ++fj) acc[fj][hm] = mfma16(aW[fj], bH, acc[fj][hm]);
    }
  }
  // ---- chunk 1: neighbor mean ----
#pragma unroll
  for (int ks=0; ks<4; ++ks){
    const int kk = ks*32 + kb;
    short8 aW[4];
#pragma unroll
    for (int fj=0; fj<4; ++fj){
      const int feat = 64*wc + 16*fj + cB;
      aW[fj] = *(const short8*)(Wt + (u32)feat*256 + 128 + kk);
    }
#pragma unroll
    for (int hm=0; hm<4; ++hm){
      short8 bH;
      if constexpr (EMBED) bH = synth8(mx[hm], We+kk, be+kk);
      else {
        short8 n0 = *(const short8*)(hin + (size_t)r0[hm]*HID + kk);
        short8 n1 = *(const short8*)(hin + (size_t)r1[hm]*HID + kk);
        short8 n2 = *(const short8*)(hin + (size_t)r2[hm]*HID + kk);
        short8 n3 = *(const short8*)(hin + (size_t)r3[hm]*HID + kk);
        bH = avg4(n0,n1,n2,n3, fw0[hm],fw1[hm],fw2[hm],fw3[hm]);
      }
#pragma unroll
      for (int fj=0; fj<4; ++fj) acc[fj][hm] = mfma16(aW[fj], bH, acc[fj][hm]);
    }
  }

  // ---- epilogue: bias + relu + LN + transposed coalesced store ----
  float4 bias4[4], g4[4], b4[4];
#pragma unroll
  for (int fj=0; fj<4; ++fj){
    const int f0 = 64*wc + 16*fj + 4*rg;
    bias4[fj] = *(const float4*)(bias + f0);
    g4[fj]    = *(const float4*)(lng  + f0);
    b4[fj]    = *(const float4*)(lnb  + f0);
  }
  float2* red = (float2*)trBuf;   // [RPB][2]

#pragma unroll
  for (int hm=0; hm<4; ++hm){
    float s1 = 0.f, s2 = 0.f;
#pragma unroll
    for (int fj=0; fj<4; ++fj){
#pragma unroll
      for (int rr=0; rr<4; ++rr){
        const float bb = (rr==0)?bias4[fj].x:(rr==1)?bias4[fj].y:(rr==2)?bias4[fj].z:bias4[fj].w;
        float y = fmaxf(acc[fj][hm][rr] + bb, 0.f);
        acc[fj][hm][rr] = y;
        s1 += y; s2 += y*y;
      }
    }
    s1 += __shfl_xor(s1,16); s1 += __shfl_xor(s1,32);
    s2 += __shfl_xor(s2,16); s2 += __shfl_xor(s2,32);
    if (rg == 0){
      const int rib = 64*wr + 16*hm + cB;
      red[rib*2 + wc] = make_float2(s1, s2);
    }
  }
  __syncthreads();

  float mu4[4], rs4[4];
#pragma unroll
  for (int hm=0; hm<4; ++hm){
    const int rib = 64*wr + 16*hm + cB;
    const float2 A = red[rib*2], B = red[rib*2+1];
    const float s1 = A.x + B.x, s2 = A.y + B.y;
    const float mu  = s1 * (1.f/128.f);
    const float var = s2 * (1.f/128.f) - mu*mu;
    mu4[hm] = mu;
    rs4[hm] = rsqrtf(var + 1e-5f);
  }
  __syncthreads();   // red reads done before trBuf writes clobber it

#pragma unroll
  for (int hm=0; hm<4; ++hm){
    const int rib = 64*wr + 16*hm + cB;
    const u32 sw = ((u32)(rib & 7)) << 4;
    char* rowp = (char*)trBuf + (u32)rib*256;
    const float mu = mu4[hm], rs = rs4[hm];
#pragma unroll
    for (int fj=0; fj<4; ++fj){
      const float y0 = fmaf((acc[fj][hm][0]-mu)*rs, g4[fj].x, b4[fj].x);
      const float y1 = fmaf((acc[fj][hm][1]-mu)*rs, g4[fj].y, b4[fj].y);
      const float y2 = fmaf((acc[fj][hm][2]-mu)*rs, g4[fj].z, b4[fj].z);
      const float y3 = fmaf((acc[fj][hm][3]-mu)*rs, g4[fj].w, b4[fj].w);
      const u32 off = (u32)(128*wc + 32*fj + 8*rg);
      *(u32*)(rowp + ((off    ) ^ sw)) = cvtpk(y0, y1);
      *(u32*)(rowp + ((off + 4) ^ sw)) = cvtpk(y2, y3);
    }
  }
  __syncthreads();

  const int orow = t >> 1, half = t & 1;
  const u32 sw2 = ((u32)(orow & 7)) << 4;
  u16* dst = hout + (size_t)(m0 + orow)*HID + half*64;
  const char* srow = (const char*)trBuf + (u32)orow*256;
#pragma unroll
  for (int i=0; i<8; ++i){
    short8 v = *(const short8*)(srow + (((u32)(half*128 + 16*i)) ^ sw2));
    *(short8*)(dst + i*8) = v;
  }
}

// Transpose gnn_W [4][256k][128j] f32 -> Wt [4][128j][256k] bf16
__global__ void prep_k(const float* __restrict__ gw, u16* __restrict__ Wt){
  const int idx = blockIdx.x*256 + threadIdx.x;   // 131072
  const int lay = idx >> 15;
  const int r   = idx & 32767;
  const int j   = r >> 8;
  const int k   = r & 255;
  Wt[idx] = f2bf(gw[lay*32768 + k*128 + j]);
}

// stage 1 of graph mean: 8 partials per batch image
__global__ void mean1_k(const u16* __restrict__ h, float* __restrict__ partial){
  __shared__ float red[16][16][8];
  const int blk = blockIdx.x;                     // 1024 = 128 b x 8 s
  const int b = blk >> 3, s = blk & 7;
  const int t = threadIdx.x;
  const int cg = t & 15, q = t >> 4;
  const int nbeg = s*253, nend = nbeg + 253;
  float a[8] = {0.f,0.f,0.f,0.f,0.f,0.f,0.f,0.f};
  const u16* hb = h + (size_t)b * NN * HID;
  for (int n = nbeg + q; n < nend; n += 16){
    short8 v = *(const short8*)(hb + (size_t)n*HID + cg*8);
#pragma unroll
    for (int i = 0; i < 8; ++i) a[i] += bf2f((u16)v[i]);
  }
#pragma unroll
  for (int i = 0; i < 8; ++i) red[q][cg][i] = a[i];
  __syncthreads();
  if (t < 128){
    const int cc = t >> 3, i = t & 7;
    float v = 0.f;
#pragma unroll
    for (int qq = 0; qq < 16; ++qq) v += red[qq][cc][i];
    partial[((size_t)b*8 + s)*128 + t] = v;
  }
}

__global__ void mean2_k(const float* __restrict__ partial, float* __restrict__ gr){
  const int idx = blockIdx.x*256 + threadIdx.x;   // 16384
  const int b = idx >> 7, c = idx & 127;
  float a = 0.f;
#pragma unroll
  for (int s = 0; s < 8; ++s) a += partial[((size_t)b*8 + s)*128 + c];
  gr[idx] = a * (1.0f / 2024.0f);
}

__global__ void head1_k(const float* __restrict__ gr, const float* __restrict__ W1,
                        const float* __restrict__ b1, float* __restrict__ hid){
  const int idx = blockIdx.x*256 + threadIdx.x;   // 16384
  const int b = idx >> 7, j = idx & 127;
  const float* g = gr + b*128;
  float a = b1[j];
  for (int k = 0; k < 128; ++k) a = fmaf(g[k], W1[k*128 + j], a);
  hid[idx] = fmaxf(a, 0.f);
}

__global__ void head2_k(const float* __restrict__ hid, const float* __restrict__ W2,
                        const float* __restrict__ b2, float* __restrict__ out){
  const int t = threadIdx.x;                      // 256 = 128 b x 2 o
  const int b = t >> 1, o = t & 1;
  const float* hh = hid + b*128;
  float a = b2[o];
  for (int k = 0; k < 128; ++k) a = fmaf(hh[k], W2[k*2 + o], a);
  out[t] = a;
}

extern "C" void kernel_launch(void* const* d_in, const int* in_sizes, int n_in,
                              void* d_out, int out_size, void* d_ws, size_t ws_size,
                              hipStream_t stream){
  const float* x  = (const float*)d_in[0];
  const float* We = (const float*)d_in[1];
  const float* be = (const float*)d_in[2];
  const float* gW = (const float*)d_in[3];
  const float* gb = (const float*)d_in[4];
  const float* lg = (const float*)d_in[5];
  const float* lb = (const float*)d_in[6];
  const float* W1 = (const float*)d_in[7];
  const float* b1 = (const float*)d_in[8];
  const float* W2 = (const float*)d_in[9];
  const float* b2 = (const float*)d_in[10];
  float* out = (float*)d_out;

  char* w = (char*)d_ws;
  const size_t HB = (size_t)MTOT * HID * 2;       // 66,322,432 B per h buffer
  u16*   hA  = (u16*)w;
  u16*   hB  = (u16*)(w + HB);
  u16*   Wt  = (u16*)(w + 2*HB);                  // 262,144 B
  float* gr  = (float*)(w + 2*HB + 262144);       // 65,536 B
  float* hid = (float*)(w + 2*HB + 262144 + 65536);
  float* partial = (float*)w;                     // overlays hA (dead after L3)

  prep_k<<<512, 256, 0, stream>>>(gW, Wt);
  layer2_k<1><<<NBLK, 512, 0, stream>>>(nullptr, x, We, be, Wt,
                                        gb, lg, lb, hA);
  layer2_k<0><<<NBLK, 512, 0, stream>>>(hA, nullptr, nullptr, nullptr, Wt + 32768,
                                        gb + 128, lg + 128, lb + 128, hB);
  layer2_k<0><<<NBLK, 512, 0, stream>>>(hB, nullptr, nullptr, nullptr, Wt + 65536,
                                        gb + 256, lg + 256, lb + 256, hA);
  layer2_k<0><<<NBLK, 512, 0, stream>>>(hA, nullptr, nullptr, nullptr, Wt + 98304,
                                        gb + 384, lg + 384, lb + 384, hB);
  mean1_k<<<NB*8, 256, 0, stream>>>(hB, partial);
  mean2_k<<<64, 256, 0, stream>>>(partial, gr);
  head1_k<<<64, 256, 0, stream>>>(gr, W1, b1, hid);
  head2_k<<<1, 256, 0, stream>>>(hid, W2, b2, out);
}

// Round 4
// 383.274 us; speedup vs baseline: 2.4677x; 2.4677x over previous
//
#include <hip/hip_runtime.h>

typedef unsigned short u16;
typedef unsigned int   u32;
typedef __attribute__((ext_vector_type(8))) short short8;
typedef __attribute__((ext_vector_type(4))) float f32x4;

#define NN   2024
#define NB   128
#define HID  128
#define MT   128
#define MTOT (NN*NB)      // 259072
#define NBLK (MTOT/MT)    // 2024 = 8*253

__device__ __forceinline__ float bflo(u32 w){ union{u32 u; float f;}c; c.u=w<<16;        return c.f; }
__device__ __forceinline__ float bfhi(u32 w){ union{u32 u; float f;}c; c.u=w&0xffff0000u; return c.f; }
__device__ __forceinline__ float bf2f(u16 h){ union{u32 u; float f;}c; c.u=((u32)h)<<16; return c.f; }
__device__ __forceinline__ u16 f2bf(float f){ union{float f; u32 u;}c; c.f=f; return (u16)((c.u+0x7fffu+((c.u>>16)&1u))>>16); }
__device__ __forceinline__ u32 cvtpk(float lo, float hi){
  u32 r; asm("v_cvt_pk_bf16_f32 %0, %1, %2" : "=v"(r) : "v"(lo), "v"(hi)); return r;
}
__device__ __forceinline__ f32x4 mfma16(short8 a, short8 b, f32x4 c){
  return __builtin_amdgcn_mfma_f32_16x16x32_bf16(a,b,c,0,0,0);
}
__device__ __forceinline__ void glds16(const void* g, void* l){
  __builtin_amdgcn_global_load_lds((const __attribute__((address_space(1))) void*)g,
                                   (__attribute__((address_space(3))) void*)l, 16, 0, 0);
}

// weighted mean of 4 bf16x8 (weights include 1/cnt), repacked to bf16 RNE
__device__ __forceinline__ short8 avg4(short8 a0, short8 a1, short8 a2, short8 a3,
                                       float w0, float w1, float w2, float w3){
  union{short8 s; u32 u[4];} A, B, C, D, R;
  A.s=a0; B.s=a1; C.s=a2; D.s=a3;
#pragma unroll
  for (int p=0;p<4;++p){
    float lo = w0*bflo(A.u[p]); lo = fmaf(w1,bflo(B.u[p]),lo); lo = fmaf(w2,bflo(C.u[p]),lo); lo = fmaf(w3,bflo(D.u[p]),lo);
    float hi = w0*bfhi(A.u[p]); hi = fmaf(w1,bfhi(B.u[p]),hi); hi = fmaf(w2,bfhi(C.u[p]),hi); hi = fmaf(w3,bfhi(D.u[p]),hi);
    R.u[p] = cvtpk(lo, hi);
  }
  return R.s;
}

// h0 k-slice: x*We[kk..kk+7] + be[kk..kk+7] packed bf16
__device__ __forceinline__ short8 synthf(float xv, float4 w0, float4 w1, float4 b0, float4 b1){
  union{short8 s; u32 u[4];} R;
  R.u[0] = cvtpk(fmaf(xv,w0.x,b0.x), fmaf(xv,w0.y,b0.y));
  R.u[1] = cvtpk(fmaf(xv,w0.z,b0.z), fmaf(xv,w0.w,b0.w));
  R.u[2] = cvtpk(fmaf(xv,w1.x,b1.x), fmaf(xv,w1.y,b1.y));
  R.u[3] = cvtpk(fmaf(xv,w1.z,b1.z), fmaf(xv,w1.w,b1.w));
  return R.s;
}

// One GNN layer: out = LN(relu([h, agg(h)] @ W + b)) * g + beta.
// W-only LDS (64KB both K-chunks, staged once). Self + neighbor h fragments
// streamed per-lane from global; agg built in-register (avg4). One barrier
// before the merged barrier-free K-loop. 8 waves of 32rows x 64cols.
template<int EMBED>
__global__ __launch_bounds__(512, 4)
void layer3_k(const u16* __restrict__ hin, const float* __restrict__ x,
              const float* __restrict__ We, const float* __restrict__ be,
              const u16* __restrict__ Wt, const float* __restrict__ bias,
              const float* __restrict__ lng, const float* __restrict__ lnb,
              u16* __restrict__ hout)
{
  __shared__ __align__(16) char Wb[65536];   // [128 cols][256 k]*2B, row=512B, XOR-swizzled
  const int t  = threadIdx.x;
  const int l  = t & 63;
  const int wv = t >> 6, wr = wv >> 1, wc = wv & 1;
  const int cB = l & 15, rg = l >> 4;

  // XCD-chunked bijective swizzle: 2024 = 8*253
  const int orig = blockIdx.x;
  const int m0 = ((orig & 7)*253 + (orig >> 3)) * MT;

  // ---- stage W (both chunks, 64KB) via glds, inverse-swizzled source ----
  {
    const int gl = l >> 5, gc = l & 31;
#pragma unroll
    for (int i = 0; i < 8; ++i){
      const int col = 16*wv + 2*i + gl;
      const int cs  = gc ^ (col & 7);
      glds16(Wt + (u32)col*256 + (u32)cs*8, Wb + (u32)(wv*8 + i)*1024);
    }
  }

  // ---- per-row info (2 m-rows per lane) ----
  u32 offS[2], offN[2][4];
  float nw[2][4];
  float xs[2], mx[2];
#pragma unroll
  for (int m = 0; m < 2; ++m){
    const int row = m0 + 32*wr + 16*m + cB;
    const int nd  = row % NN;
    const int v0 = (nd >= 45), v1 = (nd <= NN-46), v2 = (nd >= 1), v3 = (nd <= NN-2);
    const int cnt = v0+v1+v2+v3;
    const float inv = (cnt==4) ? 0.25f : ((cnt==3) ? (1.f/3.f) : 0.5f);
    nw[m][0] = v0 ? inv : 0.f; nw[m][1] = v1 ? inv : 0.f;
    nw[m][2] = v2 ? inv : 0.f; nw[m][3] = v3 ? inv : 0.f;
    const int r0 = v0 ? row-45 : row, r1 = v1 ? row+45 : row;
    const int r2 = v2 ? row-1  : row, r3 = v3 ? row+1  : row;
    offS[m]    = (u32)row * 256u;
    offN[m][0] = (u32)r0 * 256u; offN[m][1] = (u32)r1 * 256u;
    offN[m][2] = (u32)r2 * 256u; offN[m][3] = (u32)r3 * 256u;
    if constexpr (EMBED){
      xs[m] = x[row];
      mx[m] = nw[m][0]*x[r0] + nw[m][1]*x[r1] + nw[m][2]*x[r2] + nw[m][3]*x[r3];
    }
  }

  f32x4 acc[2][4];
#pragma unroll
  for (int m = 0; m < 2; ++m)
#pragma unroll
    for (int j = 0; j < 4; ++j)
      acc[m][j] = (f32x4){0.f,0.f,0.f,0.f};

  __syncthreads();   // W resident

  const char* hb  = (const char*)hin;
  const u32 wsz   = ((u32)(cB & 7)) << 4;
  const u32 rg16  = ((u32)rg) << 4;
  const char* wp[4];
#pragma unroll
  for (int j = 0; j < 4; ++j)
    wp[j] = Wb + (u32)(64*wc + 16*j + cB)*512;

  // self double-buffer prologue (ks=0)
  short8 sC0, sC1;
  if constexpr (!EMBED){
    sC0 = *(const short8*)(hb + offS[0] + rg16);
    sC1 = *(const short8*)(hb + offS[1] + rg16);
  }

  // ---- merged barrier-free K-loop: 4 ks x (chunk0 self + chunk1 agg) ----
#pragma unroll
  for (int ks = 0; ks < 4; ++ks){
    const u32 kb = (u32)ks*64 + rg16;        // byte offset of k-slice within a 256B h-row
    // issue neighbor batch for this ks
    short8 n00,n01,n02,n03, n10,n11,n12,n13;
    float4 we0, we1, bb0, bb1;
    if constexpr (!EMBED){
      n00 = *(const short8*)(hb + offN[0][0] + kb);
      n01 = *(const short8*)(hb + offN[0][1] + kb);
      n02 = *(const short8*)(hb + offN[0][2] + kb);
      n03 = *(const short8*)(hb + offN[0][3] + kb);
      n10 = *(const short8*)(hb + offN[1][0] + kb);
      n11 = *(const short8*)(hb + offN[1][1] + kb);
      n12 = *(const short8*)(hb + offN[1][2] + kb);
      n13 = *(const short8*)(hb + offN[1][3] + kb);
    } else {
      we0 = *(const float4*)(We + ks*32 + rg*8);
      we1 = *(const float4*)(We + ks*32 + rg*8 + 4);
      bb0 = *(const float4*)(be + ks*32 + rg*8);
      bb1 = *(const float4*)(be + ks*32 + rg*8 + 4);
      sC0 = synthf(xs[0], we0, we1, bb0, bb1);
      sC1 = synthf(xs[1], we0, we1, bb0, bb1);
    }
    // issue next self batch
    short8 sN0, sN1;
    if constexpr (!EMBED){
      if (ks < 3){
        sN0 = *(const short8*)(hb + offS[0] + kb + 64);
        sN1 = *(const short8*)(hb + offS[1] + kb + 64);
      }
    }
    // chunk0 MFMAs (self)
    {
      const u32 a0 = kb ^ wsz;
#pragma unroll
      for (int j = 0; j < 4; ++j){
        short8 w = *(const short8*)(wp[j] + a0);
        acc[0][j] = mfma16(sC0, w, acc[0][j]);
        acc[1][j] = mfma16(sC1, w, acc[1][j]);
      }
    }
    // build agg fragments
    short8 ag0, ag1;
    if constexpr (!EMBED){
      ag0 = avg4(n00,n01,n02,n03, nw[0][0],nw[0][1],nw[0][2],nw[0][3]);
      ag1 = avg4(n10,n11,n12,n13, nw[1][0],nw[1][1],nw[1][2],nw[1][3]);
    } else {
      ag0 = synthf(mx[0], we0, we1, bb0, bb1);
      ag1 = synthf(mx[1], we0, we1, bb0, bb1);
    }
    // chunk1 MFMAs (agg)
    {
      const u32 a1 = (kb + 256u) ^ wsz;
#pragma unroll
      for (int j = 0; j < 4; ++j){
        short8 w = *(const short8*)(wp[j] + a1);
        acc[0][j] = mfma16(ag0, w, acc[0][j]);
        acc[1][j] = mfma16(ag1, w, acc[1][j]);
      }
    }
    if constexpr (!EMBED){
      if (ks < 3){ sC0 = sN0; sC1 = sN1; }
    }
  }

  // ---- epilogue: bias + relu + LN + transposed coalesced store ----
  __syncthreads();                 // all waves done reading Wb
  float2* red = (float2*)Wb;       // [128 rows][2 wc] float2 = 2KB
  char* trB   = Wb + 4096;         // 32KB transpose buffer (disjoint from red)

  float b4[4], g4[4], bt4[4];
#pragma unroll
  for (int j = 0; j < 4; ++j){
    const int col = 64*wc + 16*j + cB;
    b4[j] = bias[col]; g4[j] = lng[col]; bt4[j] = lnb[col];
  }

#pragma unroll
  for (int m = 0; m < 2; ++m){
#pragma unroll
    for (int rr = 0; rr < 4; ++rr){
      float s1 = 0.f, s2 = 0.f;
#pragma unroll
      for (int j = 0; j < 4; ++j){
        float y = fmaxf(acc[m][j][rr] + b4[j], 0.f);
        acc[m][j][rr] = y;
        s1 += y; s2 += y*y;
      }
      s1 += __shfl_xor(s1,1); s1 += __shfl_xor(s1,2);
      s1 += __shfl_xor(s1,4); s1 += __shfl_xor(s1,8);
      s2 += __shfl_xor(s2,1); s2 += __shfl_xor(s2,2);
      s2 += __shfl_xor(s2,4); s2 += __shfl_xor(s2,8);
      if (cB == 0){
        const int row = 32*wr + 16*m + 4*rg + rr;
        red[row*2 + wc] = make_float2(s1, s2);
      }
    }
  }
  __syncthreads();

#pragma unroll
  for (int m = 0; m < 2; ++m){
#pragma unroll
    for (int rr = 0; rr < 4; ++rr){
      const int row = 32*wr + 16*m + 4*rg + rr;
      const float2 A = red[row*2], B = red[row*2 + 1];
      const float s1 = A.x + B.x, s2 = A.y + B.y;
      const float muv = s1 * (1.f/128.f);
      const float var = s2 * (1.f/128.f) - muv*muv;
      const float rsv = rsqrtf(var + 1e-5f);
      const u32 sw = ((u32)(row & 7)) << 4;
      char* rowp = trB + (u32)row*256;
#pragma unroll
      for (int j = 0; j < 4; ++j){
        const float y = fmaf((acc[m][j][rr]-muv)*rsv, g4[j], bt4[j]);
        const float p = __shfl_xor(y, 1);
        const u32 pk = (cB & 1) ? cvtpk(p, y) : cvtpk(y, p);
        const u32 off = ((u32)(128*wc + 32*j + 2*(cB & ~1))) ^ sw;
        *(u32*)(rowp + off) = pk;   // lane pair writes same value to same addr
      }
    }
  }
  __syncthreads();

  const int r = t >> 2, q = t & 3;
  const u32 sw2 = ((u32)(r & 7)) << 4;
  u16* dst = hout + (size_t)(m0 + r)*HID + q*32;
  const char* srow = trB + (u32)r*256;
#pragma unroll
  for (int i = 0; i < 4; ++i)
    *(short8*)(dst + i*8) = *(const short8*)(srow + (((u32)(q*64 + i*16)) ^ sw2));
}

// Transpose gnn_W [4][256k][128j] f32 -> Wt [4][128j][256k] bf16
__global__ void prep_k(const float* __restrict__ gw, u16* __restrict__ Wt){
  const int idx = blockIdx.x*256 + threadIdx.x;   // 131072
  const int lay = idx >> 15;
  const int r   = idx & 32767;
  const int j   = r >> 8;
  const int k   = r & 255;
  Wt[idx] = f2bf(gw[lay*32768 + k*128 + j]);
}

// stage 1 of graph mean: 8 partials per batch image
__global__ void mean1_k(const u16* __restrict__ h, float* __restrict__ partial){
  __shared__ float red[16][16][8];
  const int blk = blockIdx.x;                     // 1024 = 128 b x 8 s
  const int b = blk >> 3, s = blk & 7;
  const int t = threadIdx.x;
  const int cg = t & 15, q = t >> 4;
  const int nbeg = s*253, nend = nbeg + 253;
  float a[8] = {0.f,0.f,0.f,0.f,0.f,0.f,0.f,0.f};
  const u16* hb = h + (size_t)b * NN * HID;
  for (int n = nbeg + q; n < nend; n += 16){
    short8 v = *(const short8*)(hb + (size_t)n*HID + cg*8);
#pragma unroll
    for (int i = 0; i < 8; ++i) a[i] += bf2f((u16)v[i]);
  }
#pragma unroll
  for (int i = 0; i < 8; ++i) red[q][cg][i] = a[i];
  __syncthreads();
  if (t < 128){
    const int cc = t >> 3, i = t & 7;
    float v = 0.f;
#pragma unroll
    for (int qq = 0; qq < 16; ++qq) v += red[qq][cc][i];
    partial[((size_t)b*8 + s)*128 + t] = v;
  }
}

__global__ void mean2_k(const float* __restrict__ partial, float* __restrict__ gr){
  const int idx = blockIdx.x*256 + threadIdx.x;   // 16384
  const int b = idx >> 7, c = idx & 127;
  float a = 0.f;
#pragma unroll
  for (int s = 0; s < 8; ++s) a += partial[((size_t)b*8 + s)*128 + c];
  gr[idx] = a * (1.0f / 2024.0f);
}

__global__ void head1_k(const float* __restrict__ gr, const float* __restrict__ W1,
                        const float* __restrict__ b1, float* __restrict__ hid){
  const int idx = blockIdx.x*256 + threadIdx.x;   // 16384
  const int b = idx >> 7, j = idx & 127;
  const float* g = gr + b*128;
  float a = b1[j];
  for (int k = 0; k < 128; ++k) a = fmaf(g[k], W1[k*128 + j], a);
  hid[idx] = fmaxf(a, 0.f);
}

__global__ void head2_k(const float* __restrict__ hid, const float* __restrict__ W2,
                        const float* __restrict__ b2, float* __restrict__ out){
  const int t = threadIdx.x;                      // 256 = 128 b x 2 o
  const int b = t >> 1, o = t & 1;
  const float* hh = hid + b*128;
  float a = b2[o];
  for (int k = 0; k < 128; ++k) a = fmaf(hh[k], W2[k*2 + o], a);
  out[t] = a;
}

extern "C" void kernel_launch(void* const* d_in, const int* in_sizes, int n_in,
                              void* d_out, int out_size, void* d_ws, size_t ws_size,
                              hipStream_t stream){
  const float* x  = (const float*)d_in[0];
  const float* We = (const float*)d_in[1];
  const float* be = (const float*)d_in[2];
  const float* gW = (const float*)d_in[3];
  const float* gb = (const float*)d_in[4];
  const float* lg = (const float*)d_in[5];
  const float* lb = (const float*)d_in[6];
  const float* W1 = (const float*)d_in[7];
  const float* b1 = (const float*)d_in[8];
  const float* W2 = (const float*)d_in[9];
  const float* b2 = (const float*)d_in[10];
  float* out = (float*)d_out;

  char* w = (char*)d_ws;
  const size_t HB = (size_t)MTOT * HID * 2;       // 66,322,432 B per h buffer
  u16*   hA  = (u16*)w;
  u16*   hB  = (u16*)(w + HB);
  u16*   Wt  = (u16*)(w + 2*HB);                  // 262,144 B
  float* gr  = (float*)(w + 2*HB + 262144);       // 65,536 B
  float* hid = (float*)(w + 2*HB + 262144 + 65536);
  float* partial = (float*)w;                     // overlays hA (dead after L3)

  prep_k<<<512, 256, 0, stream>>>(gW, Wt);
  layer3_k<1><<<NBLK, 512, 0, stream>>>(nullptr, x, We, be, Wt,
                                        gb, lg, lb, hA);
  layer3_k<0><<<NBLK, 512, 0, stream>>>(hA, nullptr, nullptr, nullptr, Wt + 32768,
                                        gb + 128, lg + 128, lb + 128, hB);
  layer3_k<0><<<NBLK, 512, 0, stream>>>(hB, nullptr, nullptr, nullptr, Wt + 65536,
                                        gb + 256, lg + 256, lb + 256, hA);
  layer3_k<0><<<NBLK, 512, 0, stream>>>(hA, nullptr, nullptr, nullptr, Wt + 98304,
                                        gb + 384, lg + 384, lb + 384, hB);
  mean1_k<<<NB*8, 256, 0, stream>>>(hB, partial);
  mean2_k<<<64, 256, 0, stream>>>(partial, gr);
  head1_k<<<64, 256, 0, stream>>>(gr, W1, b1, hid);
  head2_k<<<1, 256, 0, stream>>>(hid, W2, b2, out);
}

// Round 5
// 381.768 us; speedup vs baseline: 2.4774x; 1.0039x over previous
//
#include <hip/hip_runtime.h>

typedef unsigned short u16;
typedef unsigned int   u32;
typedef __attribute__((ext_vector_type(8))) short short8;
typedef __attribute__((ext_vector_type(4))) float f32x4;

#define NN   2024
#define NB   128
#define HID  128
#define MT   128
#define MTOT (NN*NB)      // 259072
#define NBLK (MTOT/MT)    // 2024 = 8*253

__device__ __forceinline__ float bflo(u32 w){ union{u32 u; float f;}c; c.u=w<<16;        return c.f; }
__device__ __forceinline__ float bfhi(u32 w){ union{u32 u; float f;}c; c.u=w&0xffff0000u; return c.f; }
__device__ __forceinline__ float bf2f(u16 h){ union{u32 u; float f;}c; c.u=((u32)h)<<16; return c.f; }
__device__ __forceinline__ u16 f2bf(float f){ union{float f; u32 u;}c; c.f=f; return (u16)((c.u+0x7fffu+((c.u>>16)&1u))>>16); }
__device__ __forceinline__ u32 cvtpk(float lo, float hi){
  u32 r; asm("v_cvt_pk_bf16_f32 %0, %1, %2" : "=v"(r) : "v"(lo), "v"(hi)); return r;
}
__device__ __forceinline__ f32x4 mfma16(short8 a, short8 b, f32x4 c){
  return __builtin_amdgcn_mfma_f32_16x16x32_bf16(a,b,c,0,0,0);
}
__device__ __forceinline__ void glds16(const void* g, void* l){
  __builtin_amdgcn_global_load_lds((const __attribute__((address_space(1))) void*)g,
                                   (__attribute__((address_space(3))) void*)l, 16, 0, 0);
}

// weighted sum of 4 bf16x8 (weights include 1/cnt), repacked bf16 RNE
__device__ __forceinline__ short8 aggc(short8 a0, short8 a1, short8 a2, short8 a3,
                                       float w0, float w1, float w2, float w3){
  union{short8 s; u32 u[4];} A, B, C, D, R;
  A.s=a0; B.s=a1; C.s=a2; D.s=a3;
#pragma unroll
  for (int p=0;p<4;++p){
    float lo = w0*bflo(A.u[p]); lo = fmaf(w1,bflo(B.u[p]),lo); lo = fmaf(w2,bflo(C.u[p]),lo); lo = fmaf(w3,bflo(D.u[p]),lo);
    float hi = w0*bfhi(A.u[p]); hi = fmaf(w1,bfhi(B.u[p]),hi); hi = fmaf(w2,bfhi(C.u[p]),hi); hi = fmaf(w3,bfhi(D.u[p]),hi);
    R.u[p] = cvtpk(lo, hi);
  }
  return R.s;
}

// GNN layer l>=2: out = LN(relu(h@W0 + agg(h)@W1 + b)) * g + beta.
// 256 threads = 4 waves (2 row x 2 col), wave tile 64 rows x 64 feats, acc[4][4].
// LDS 64KB: [0,32K) = W half-chunk (staged twice; epilogue: red), [32K,64K) = agg tile (epilogue: transpose).
__global__ __launch_bounds__(256, 2)
void layerG_k(const u16* __restrict__ hin, const u16* __restrict__ Wt,
              const float* __restrict__ bias, const float* __restrict__ lng,
              const float* __restrict__ lnb, u16* __restrict__ hout)
{
  __shared__ __align__(16) char lds[65536];
  char* Wl = lds;
  char* Ag = lds + 32768;

  const int t  = threadIdx.x;
  const int l  = t & 63;
  const int wv = t >> 6;          // 0..3
  const int wr = wv >> 1, wc = wv & 1;
  const int cB = l & 15, rg = l >> 4;

  const int orig = blockIdx.x;                        // 2024 = 8*253
  const int m0 = ((orig & 7)*253 + (orig >> 3)) * MT;

  const char* hb = (const char*)hin;

  // ---- issue W0 stage via global_load_lds (zero VGPR) ----
  {
#pragma unroll
    for (int i = 0; i < 8; ++i){
      const int slot = wv*8 + i;                      // 32 slots x 1KB
      const int col  = slot*4 + (l >> 4);
      const u32 se   = (u32)col*256 + ((((u32)(l & 15))*8) ^ (((u32)(col & 7))<<3));
      glds16(Wt + se, Wl + (u32)slot*1024);
    }
  }

  // ---- agg geometry (thread owns row r, feat-half hf) ----
  const int r  = t >> 1;          // 0..127
  const int hf = t & 1;
  const int grow = m0 + r;
  const int nd = grow % NN;
  const int v0 = (nd >= 45), v1 = (nd <= NN-46), v2 = (nd >= 1), v3 = (nd <= NN-2);
  const int cnt = v0+v1+v2+v3;
  const float inv = (cnt==4) ? 0.25f : ((cnt==3) ? (1.f/3.f) : 0.5f);
  const float w0 = v0 ? inv : 0.f, w1 = v1 ? inv : 0.f;
  const float w2 = v2 ? inv : 0.f, w3 = v3 ? inv : 0.f;
  const u32 nb0 = (u32)(v0 ? grow-45 : grow)*256u + (u32)hf*128u;
  const u32 nb1 = (u32)(v1 ? grow+45 : grow)*256u + (u32)hf*128u;
  const u32 nb2 = (u32)(v2 ? grow-1  : grow)*256u + (u32)hf*128u;
  const u32 nb3 = (u32)(v3 ? grow+1  : grow)*256u + (u32)hf*128u;

  // prefetch agg chunks 0..3 (feats hf*64 + [0,32))
  short8 nA[4], nB_[4], nC[4], nD[4];
#pragma unroll
  for (int c = 0; c < 4; ++c){
    nA[c]  = *(const short8*)(hb + nb0 + c*16);
    nB_[c] = *(const short8*)(hb + nb1 + c*16);
    nC[c]  = *(const short8*)(hb + nb2 + c*16);
    nD[c]  = *(const short8*)(hb + nb3 + c*16);
  }

  f32x4 acc[4][4];
#pragma unroll
  for (int m = 0; m < 4; ++m)
#pragma unroll
    for (int j = 0; j < 4; ++j)
      acc[m][j] = (f32x4){0.f,0.f,0.f,0.f};

  __syncthreads();   // B1: W0 resident

  // ---- R1: W1 reg-load issue + ch0 GEMM + agg build ----
  // W1 reg stage: thread covers col c1 = t>>1, k-half hk = t&1 (64 elems)
  const int c1 = t >> 1, hk = t & 1;
  short8 w1r[8];
  {
    const u16* s1p = Wt + (u32)c1*256 + 128 + (u32)hk*64;
#pragma unroll
    for (int i = 0; i < 8; ++i) w1r[i] = *(const short8*)(s1p + i*8);
  }

  const u32 kswz = ((u32)(cB & 7)) << 4;
  const char* wp[4];
#pragma unroll
  for (int j = 0; j < 4; ++j)
    wp[j] = Wl + (u32)(64*wc + 16*j + cB)*256;
  const char* selfp = hb + ((u32)(m0 + 64*wr + cB))*256u + (u32)rg*16;

  // ch0: self h x W0
#pragma unroll
  for (int ks = 0; ks < 4; ++ks){
    const u32 ka = ((u32)ks*64 + (u32)rg*16) ^ kswz;
    short8 wf[4];
#pragma unroll
    for (int j = 0; j < 4; ++j) wf[j] = *(const short8*)(wp[j] + ka);
#pragma unroll
    for (int m = 0; m < 4; ++m){
      short8 s = *(const short8*)(selfp + m*4096 + ks*64);
#pragma unroll
      for (int j = 0; j < 4; ++j) acc[m][j] = mfma16(s, wf[j], acc[m][j]);
    }
  }

  // agg build: chunks 0..3 from prefetch, 4..7 fresh
  {
    char* arow = Ag + (u32)r*256;
    const u32 asw = ((u32)(r & 7)) << 4;
#pragma unroll
    for (int c = 0; c < 4; ++c){
      short8 v = aggc(nA[c], nB_[c], nC[c], nD[c], w0, w1, w2, w3);
      *(short8*)(arow + (((u32)(hf*128 + c*16)) ^ asw)) = v;
    }
    short8 mA[4], mB[4], mC[4], mD[4];
#pragma unroll
    for (int c = 0; c < 4; ++c){
      mA[c] = *(const short8*)(hb + nb0 + 64 + c*16);
      mB[c] = *(const short8*)(hb + nb1 + 64 + c*16);
      mC[c] = *(const short8*)(hb + nb2 + 64 + c*16);
      mD[c] = *(const short8*)(hb + nb3 + 64 + c*16);
    }
#pragma unroll
    for (int c = 0; c < 4; ++c){
      short8 v = aggc(mA[c], mB[c], mC[c], mD[c], w0, w1, w2, w3);
      *(short8*)(arow + (((u32)(hf*128 + 64 + c*16)) ^ asw)) = v;
    }
  }
  __syncthreads();   // B2: ch0 W0-reads done, agg tile ready

  // ---- R2: write W1 into Wl ----
  {
    char* wdst = Wl + (u32)c1*256;
#pragma unroll
    for (int i = 0; i < 8; ++i)
      *(short8*)(wdst + (((u32)(hk*128 + i*16)) ^ (((u32)(c1 & 7))<<4))) = w1r[i];
  }
  __syncthreads();   // B3: W1 resident

  // ---- R3: ch1 GEMM: agg(LDS) x W1 ----
  {
    const char* agp = Ag + (u32)(64*wr + cB)*256;
#pragma unroll
    for (int ks = 0; ks < 4; ++ks){
      const u32 ka = ((u32)ks*64 + (u32)rg*16) ^ kswz;
      short8 wf[4];
#pragma unroll
      for (int j = 0; j < 4; ++j) wf[j] = *(const short8*)(wp[j] + ka);
#pragma unroll
      for (int m = 0; m < 4; ++m){
        short8 a = *(const short8*)(agp + m*4096 + ka);
#pragma unroll
        for (int j = 0; j < 4; ++j) acc[m][j] = mfma16(a, wf[j], acc[m][j]);
      }
    }
  }
  __syncthreads();   // B4: ch1 LDS reads done -> safe to overlay

  // ---- epilogue ----
  float2* red = (float2*)Wl;        // [128 rows][2 wc]
  float b4[4], g4[4], bt4[4];
#pragma unroll
  for (int j = 0; j < 4; ++j){
    const int col = 64*wc + 16*j + cB;
    b4[j] = bias[col]; g4[j] = lng[col]; bt4[j] = lnb[col];
  }
#pragma unroll
  for (int m = 0; m < 4; ++m){
#pragma unroll
    for (int rr = 0; rr < 4; ++rr){
      float s1 = 0.f, s2 = 0.f;
#pragma unroll
      for (int j = 0; j < 4; ++j){
        float y = fmaxf(acc[m][j][rr] + b4[j], 0.f);
        acc[m][j][rr] = y;
        s1 += y; s2 = fmaf(y, y, s2);
      }
      s1 += __shfl_xor(s1,1); s1 += __shfl_xor(s1,2);
      s1 += __shfl_xor(s1,4); s1 += __shfl_xor(s1,8);
      s2 += __shfl_xor(s2,1); s2 += __shfl_xor(s2,2);
      s2 += __shfl_xor(s2,4); s2 += __shfl_xor(s2,8);
      if (cB == 0){
        const int rl = 64*wr + 16*m + 4*rg + rr;
        red[rl*2 + wc] = make_float2(s1, s2);
      }
    }
  }
  __syncthreads();   // B5: red complete

#pragma unroll
  for (int m = 0; m < 4; ++m){
#pragma unroll
    for (int rr = 0; rr < 4; ++rr){
      const int rl = 64*wr + 16*m + 4*rg + rr;
      const float2 A = red[rl*2], B = red[rl*2+1];
      const float s1 = A.x + B.x, s2 = A.y + B.y;
      const float muv = s1 * (1.f/128.f);
      const float var = s2 * (1.f/128.f) - muv*muv;
      const float rsv = rsqrtf(var + 1e-5f);
      const u32 sw = ((u32)(rl & 7)) << 4;
      char* rowp = Ag + (u32)rl*256;
#pragma unroll
      for (int j = 0; j < 4; ++j){
        const float y = fmaf((acc[m][j][rr]-muv)*rsv, g4[j], bt4[j]);
        const float p = __shfl_xor(y, 1);
        const u32 pk = (cB & 1) ? cvtpk(p, y) : cvtpk(y, p);
        const u32 off = ((u32)(128*wc + 32*j + 2*(cB & ~1))) ^ sw;
        *(u32*)(rowp + off) = pk;
      }
    }
  }
  __syncthreads();   // B6: transpose tile ready

  const int r2 = t >> 1, q2 = t & 1;
  const u32 sw2 = ((u32)(r2 & 7)) << 4;
  u16* dst = hout + (size_t)(m0 + r2)*HID + q2*64;
  const char* srow = Ag + (u32)r2*256;
#pragma unroll
  for (int i = 0; i < 8; ++i)
    *(short8*)(dst + i*8) = *(const short8*)(srow + (((u32)(q2*128 + i*16)) ^ sw2));
}

// Layer 1 (rank-1 shortcut): h1 = LN(relu(x*u0 + mx*u1 + c)) * g + beta
__global__ __launch_bounds__(256, 4)
void l1_k(const float* __restrict__ x, const float* __restrict__ uvec,
          const float* __restrict__ lng, const float* __restrict__ lnb,
          u16* __restrict__ hout)
{
  __shared__ float su[384];
  __shared__ float sg[128], sb[128];
  const int t = threadIdx.x;
  const int m0 = ((blockIdx.x & 7)*253 + (blockIdx.x >> 3)) * MT;
  for (int i = t; i < 384; i += 256) su[i] = uvec[i];
  if (t < 128){ sg[t] = lng[t]; sb[t] = lnb[t]; }
  __syncthreads();

  const int r = t >> 1, hf = t & 1;
  const int grow = m0 + r;
  const int nd = grow % NN;
  const int v0 = (nd >= 45), v1 = (nd <= NN-46), v2 = (nd >= 1), v3 = (nd <= NN-2);
  const int cnt = v0+v1+v2+v3;
  const float inv = (cnt==4) ? 0.25f : ((cnt==3) ? (1.f/3.f) : 0.5f);
  const float xv = x[grow];
  float mx = 0.f;
  if (v0) mx += x[grow-45];
  if (v1) mx += x[grow+45];
  if (v2) mx += x[grow-1];
  if (v3) mx += x[grow+1];
  mx *= inv;

  const int fb = hf*64;
  float4 yv[16];
  float s1 = 0.f, s2 = 0.f;
#pragma unroll
  for (int i = 0; i < 16; ++i){
    const float4 a = *(const float4*)(su + fb + i*4);
    const float4 b = *(const float4*)(su + 128 + fb + i*4);
    const float4 c = *(const float4*)(su + 256 + fb + i*4);
    float4 y;
    y.x = fmaxf(fmaf(xv, a.x, fmaf(mx, b.x, c.x)), 0.f);
    y.y = fmaxf(fmaf(xv, a.y, fmaf(mx, b.y, c.y)), 0.f);
    y.z = fmaxf(fmaf(xv, a.z, fmaf(mx, b.z, c.z)), 0.f);
    y.w = fmaxf(fmaf(xv, a.w, fmaf(mx, b.w, c.w)), 0.f);
    yv[i] = y;
    s1 += y.x + y.y + y.z + y.w;
    s2 = fmaf(y.x,y.x, fmaf(y.y,y.y, fmaf(y.z,y.z, fmaf(y.w,y.w, s2))));
  }
  s1 += __shfl_xor(s1, 1);
  s2 += __shfl_xor(s2, 1);
  const float muv = s1 * (1.f/128.f);
  const float var = s2 * (1.f/128.f) - muv*muv;
  const float rsv = rsqrtf(var + 1e-5f);

  u16* dst = hout + (size_t)grow*HID + fb;
#pragma unroll
  for (int i = 0; i < 8; ++i){
    const float4 ya = yv[2*i], yb = yv[2*i+1];
    const float4 ga = *(const float4*)(sg + fb + i*8);
    const float4 gb2 = *(const float4*)(sg + fb + i*8 + 4);
    const float4 ba = *(const float4*)(sb + fb + i*8);
    const float4 bb = *(const float4*)(sb + fb + i*8 + 4);
    u32 o0 = cvtpk(fmaf((ya.x-muv)*rsv, ga.x, ba.x), fmaf((ya.y-muv)*rsv, ga.y, ba.y));
    u32 o1 = cvtpk(fmaf((ya.z-muv)*rsv, ga.z, ba.z), fmaf((ya.w-muv)*rsv, ga.w, ba.w));
    u32 o2 = cvtpk(fmaf((yb.x-muv)*rsv, gb2.x, bb.x), fmaf((yb.y-muv)*rsv, gb2.y, bb.y));
    u32 o3 = cvtpk(fmaf((yb.z-muv)*rsv, gb2.z, bb.z), fmaf((yb.w-muv)*rsv, gb2.w, bb.w));
    uint4 pk = make_uint4(o0, o1, o2, o3);
    *(uint4*)(dst + i*8) = pk;
  }
}

// Transpose gnn_W [4][256k][128j] f32 -> Wt [4][128j][256k] bf16
__global__ void prep_k(const float* __restrict__ gw, u16* __restrict__ Wt){
  const int idx = blockIdx.x*256 + threadIdx.x;   // 131072
  const int lay = idx >> 15;
  const int r   = idx & 32767;
  const int j   = r >> 8;
  const int k   = r & 255;
  Wt[idx] = f2bf(gw[lay*32768 + k*128 + j]);
}

// u0 = We@W0_l0, u1 = We@W1_l0, c = be@(W0+W1) + b_l0
__global__ void prep2_k(const float* __restrict__ We, const float* __restrict__ be,
                        const float* __restrict__ gW, const float* __restrict__ gb,
                        float* __restrict__ uvec){
  const int f = threadIdx.x;  // 128
  float u0 = 0.f, u1 = 0.f, c = 0.f;
  for (int k = 0; k < 128; ++k){
    const float a = gW[k*128 + f];
    const float b = gW[(128+k)*128 + f];
    u0 = fmaf(We[k], a, u0);
    u1 = fmaf(We[k], b, u1);
    c  = fmaf(be[k], a + b, c);
  }
  uvec[f] = u0; uvec[128+f] = u1; uvec[256+f] = c + gb[f];
}

// stage 1 of graph mean: 8 partials per batch image
__global__ void mean1_k(const u16* __restrict__ h, float* __restrict__ partial){
  __shared__ float red[16][16][8];
  const int blk = blockIdx.x;                     // 1024 = 128 b x 8 s
  const int b = blk >> 3, s = blk & 7;
  const int t = threadIdx.x;
  const int cg = t & 15, q = t >> 4;
  const int nbeg = s*253, nend = nbeg + 253;
  float a[8] = {0.f,0.f,0.f,0.f,0.f,0.f,0.f,0.f};
  const u16* hb = h + (size_t)b * NN * HID;
  for (int n = nbeg + q; n < nend; n += 16){
    short8 v = *(const short8*)(hb + (size_t)n*HID + cg*8);
#pragma unroll
    for (int i = 0; i < 8; ++i) a[i] += bf2f((u16)v[i]);
  }
#pragma unroll
  for (int i = 0; i < 8; ++i) red[q][cg][i] = a[i];
  __syncthreads();
  if (t < 128){
    const int cc = t >> 3, i = t & 7;
    float v = 0.f;
#pragma unroll
    for (int qq = 0; qq < 16; ++qq) v += red[qq][cc][i];
    partial[((size_t)b*8 + s)*128 + t] = v;
  }
}

__global__ void mean2_k(const float* __restrict__ partial, float* __restrict__ gr){
  const int idx = blockIdx.x*256 + threadIdx.x;   // 16384
  const int b = idx >> 7, c = idx & 127;
  float a = 0.f;
#pragma unroll
  for (int s = 0; s < 8; ++s) a += partial[((size_t)b*8 + s)*128 + c];
  gr[idx] = a * (1.0f / 2024.0f);
}

__global__ void head1_k(const float* __restrict__ gr, const float* __restrict__ W1,
                        const float* __restrict__ b1, float* __restrict__ hid){
  const int idx = blockIdx.x*256 + threadIdx.x;   // 16384
  const int b = idx >> 7, j = idx & 127;
  const float* g = gr + b*128;
  float a = b1[j];
  for (int k = 0; k < 128; ++k) a = fmaf(g[k], W1[k*128 + j], a);
  hid[idx] = fmaxf(a, 0.f);
}

__global__ void head2_k(const float* __restrict__ hid, const float* __restrict__ W2,
                        const float* __restrict__ b2, float* __restrict__ out){
  const int t = threadIdx.x;                      // 256 = 128 b x 2 o
  const int b = t >> 1, o = t & 1;
  const float* hh = hid + b*128;
  float a = b2[o];
  for (int k = 0; k < 128; ++k) a = fmaf(hh[k], W2[k*2 + o], a);
  out[t] = a;
}

extern "C" void kernel_launch(void* const* d_in, const int* in_sizes, int n_in,
                              void* d_out, int out_size, void* d_ws, size_t ws_size,
                              hipStream_t stream){
  const float* x  = (const float*)d_in[0];
  const float* We = (const float*)d_in[1];
  const float* be = (const float*)d_in[2];
  const float* gW = (const float*)d_in[3];
  const float* gb = (const float*)d_in[4];
  const float* lg = (const float*)d_in[5];
  const float* lb = (const float*)d_in[6];
  const float* W1 = (const float*)d_in[7];
  const float* b1 = (const float*)d_in[8];
  const float* W2 = (const float*)d_in[9];
  const float* b2 = (const float*)d_in[10];
  float* out = (float*)d_out;

  char* w = (char*)d_ws;
  const size_t HB = (size_t)MTOT * HID * 2;       // 66,322,432 B per h buffer
  u16*   hA   = (u16*)w;
  u16*   hB   = (u16*)(w + HB);
  u16*   Wt   = (u16*)(w + 2*HB);                 // 262,144 B
  float* gr   = (float*)(w + 2*HB + 262144);      // 65,536 B
  float* hid  = (float*)(w + 2*HB + 262144 + 65536);
  float* uvec = (float*)(w + 2*HB + 262144 + 131072);
  float* partial = (float*)w;                     // overlays hA (dead after layer 3)

  prep2_k<<<1, 128, 0, stream>>>(We, be, gW, gb, uvec);
  prep_k<<<512, 256, 0, stream>>>(gW, Wt);
  l1_k<<<NBLK, 256, 0, stream>>>(x, uvec, lg, lb, hA);
  layerG_k<<<NBLK, 256, 0, stream>>>(hA, Wt + 32768, gb + 128, lg + 128, lb + 128, hB);
  layerG_k<<<NBLK, 256, 0, stream>>>(hB, Wt + 65536, gb + 256, lg + 256, lb + 256, hA);
  layerG_k<<<NBLK, 256, 0, stream>>>(hA, Wt + 98304, gb + 384, lg + 384, lb + 384, hB);
  mean1_k<<<NB*8, 256, 0, stream>>>(hB, partial);
  mean2_k<<<64, 256, 0, stream>>>(partial, gr);
  head1_k<<<64, 256, 0, stream>>>(gr, W1, b1, hid);
  head2_k<<<1, 256, 0, stream>>>(hid, W2, b2, out);
}